// Round 8
// baseline (480.624 us; speedup 1.0000x reference)
//
#include <hip/hip_runtime.h>
#include <hip/hip_fp16.h>
#include <hip/hip_fp8.h>

#define NNODES 4096
#define LWALK 16
#define ODIM 8

#define FP8_SCALE 256.0f
#define FP8_INV   0.00390625f          // 1/256
#define FP8_INV2  1.52587890625e-05f   // 1/65536

typedef unsigned int uint4n __attribute__((ext_vector_type(4)));
typedef unsigned int uint2n __attribute__((ext_vector_type(2)));
typedef float float2n __attribute__((ext_vector_type(2)));

// ---------- fp8 helpers (HW cvt; format-internal-consistency is all we need) ----
__device__ __forceinline__ void dec8f(unsigned int lo, unsigned int hi, float* f) {
#if __has_builtin(__builtin_amdgcn_cvt_pk_f32_fp8)
    float2n p;
    p = __builtin_amdgcn_cvt_pk_f32_fp8((int)lo, false); f[0] = p.x; f[1] = p.y;
    p = __builtin_amdgcn_cvt_pk_f32_fp8((int)lo, true);  f[2] = p.x; f[3] = p.y;
    p = __builtin_amdgcn_cvt_pk_f32_fp8((int)hi, false); f[4] = p.x; f[5] = p.y;
    p = __builtin_amdgcn_cvt_pk_f32_fp8((int)hi, true);  f[6] = p.x; f[7] = p.y;
#else
    unsigned int w[2] = {lo, hi};
    const unsigned char* b = (const unsigned char*)w;
#pragma unroll
    for (int i = 0; i < 8; ++i) {
        __hip_fp8_e4m3 t; t.__x = b[i]; f[i] = (float)t;
    }
#endif
}

__device__ __forceinline__ void enc8f(const float* a, unsigned int* lo,
                                      unsigned int* hi) {
#if __has_builtin(__builtin_amdgcn_cvt_pk_fp8_f32)
    int l = 0, h = 0;
    l = __builtin_amdgcn_cvt_pk_fp8_f32(a[0], a[1], l, false);
    l = __builtin_amdgcn_cvt_pk_fp8_f32(a[2], a[3], l, true);
    h = __builtin_amdgcn_cvt_pk_fp8_f32(a[4], a[5], h, false);
    h = __builtin_amdgcn_cvt_pk_fp8_f32(a[6], a[7], h, true);
    *lo = (unsigned int)l; *hi = (unsigned int)h;
#else
    unsigned char b[8];
#pragma unroll
    for (int i = 0; i < 8; ++i)
        b[i] = __hip_cvt_float_to_fp8(a[i], __HIP_SATFINITE, __HIP_E4M3);
    unsigned int w[2];
    __builtin_memcpy(w, b, 8);
    *lo = w[0]; *hi = w[1];
#endif
}

// ---------- edge-index dtype detection (int32 vs int64 on device) ----------
__global__ void detect_fmt_k(const void* ei, int E, int* flag) {
    if (blockIdx.x == 0 && threadIdx.x == 0) {
        const long long* p = (const long long*)ei;
        int ok = 1;
        for (int i = 0; i < 64; ++i) {
            long long v = p[i];
            if (v < 0 || v >= NNODES) { ok = 0; break; }
        }
        *flag = ok;  // 1 => int64 layout, 0 => int32 layout
    }
}

__device__ __forceinline__ int load_idx(const void* p, int i, int fmt) {
    if (fmt) return (int)((const long long*)p)[i];
    return ((const int*)p)[i];
}

// ---------- degree + in-degree counts ----------
__global__ void build_deg_cnt_k(const void* ei, int E, int* deg, int* cnt,
                                const int* fmt) {
    int e = blockIdx.x * blockDim.x + threadIdx.x;
    if (e >= E) return;
    int f = *fmt;
    int r = load_idx(ei, e, f);
    int c = load_idx(ei, E + e, f);
    atomicAdd(&deg[r], 1);
    atomicAdd(&cnt[c], 1);
}

// ---------- exclusive scan over padded (multiple-of-8) counts ----------
__global__ void scan_k(const int* __restrict__ cnt, int* __restrict__ rowptr,
                       int* __restrict__ cursor) {
    __shared__ int sm[1024];
    int tid = threadIdx.x;
    int v0 = (cnt[4 * tid + 0] + 7) & ~7;
    int v1 = (cnt[4 * tid + 1] + 7) & ~7;
    int v2 = (cnt[4 * tid + 2] + 7) & ~7;
    int v3 = (cnt[4 * tid + 3] + 7) & ~7;
    int tsum = v0 + v1 + v2 + v3;
    sm[tid] = tsum;
    __syncthreads();
    int val = tsum;
    for (int off = 1; off < 1024; off <<= 1) {
        int t = (tid >= off) ? sm[tid - off] : 0;
        __syncthreads();
        val += t;
        sm[tid] = val;
        __syncthreads();
    }
    int excl = val - tsum;
    int p0 = excl, p1 = excl + v0, p2 = p1 + v1, p3 = p2 + v2;
    rowptr[4 * tid + 0] = p0; rowptr[4 * tid + 1] = p1;
    rowptr[4 * tid + 2] = p2; rowptr[4 * tid + 3] = p3;
    cursor[4 * tid + 0] = p0; cursor[4 * tid + 1] = p1;
    cursor[4 * tid + 2] = p2; cursor[4 * tid + 3] = p3;
    if (tid == 1023) rowptr[4096] = val;
}

// ---------- counting-sort fill of interleaved padded column-CSR ----------
__global__ void fill_csr_k(const void* ei, int E, const int* __restrict__ deg,
                           int* cursor, uint2* __restrict__ epad, const int* fmt) {
    int e = blockIdx.x * blockDim.x + threadIdx.x;
    if (e >= E) return;
    int f = *fmt;
    int r = load_idx(ei, e, f);
    int c = load_idx(ei, E + e, f);
    int pos = atomicAdd(&cursor[c], 1);
    int d = deg[r];
    float v = 1.0f / (float)(d < 1 ? 1 : d);
    epad[pos] = make_uint2((unsigned)r, __float_as_uint(v));
}

// ---------- zero-fill the padding slots (r=0, v=0 -> harmless) ----------
__global__ void pad_fill_k(const int* __restrict__ rowptr,
                           const int* __restrict__ cursor,
                           uint2* __restrict__ epad) {
    int c = blockIdx.x * blockDim.x + threadIdx.x;
    if (c >= NNODES) return;
    for (int p = cursor[c]; p < rowptr[c + 1]; ++p)
        epad[p] = make_uint2(0u, 0u);
}

// ---------- zero an fp16 buffer ----------
__global__ void zero_k(uint4n* p) {
    int i = blockIdx.x * blockDim.x + threadIdx.x;
    uint4n z = {0u, 0u, 0u, 0u};
    p[i] = z;
}

// ---------- build X1 = P^T directly from column-CSR (skips spmm step m=1) ----
// One thread per row c of X1; combines duplicate edges; extracts diag k=1.
__global__ void x1build_k(const int* __restrict__ rowptr,
                          const uint2* __restrict__ epad, __half* __restrict__ X1,
                          float* __restrict__ rw) {
    int c = blockIdx.x * blockDim.x + threadIdx.x;
    if (c >= NNODES) return;
    int beg = rowptr[c], end = rowptr[c + 1];
    float dia = 0.f;
    for (int j = beg; j < end; ++j) {
        uint2 ej = epad[j];
        float v = __uint_as_float(ej.y);
        if (v == 0.f) continue;
        bool first = true;
        for (int k = beg; k < j; ++k) {
            uint2 ek = epad[k];
            if (ek.x == ej.x && __uint_as_float(ek.y) != 0.f) { first = false; break; }
        }
        if (!first) continue;
        float s = v;
        for (int k = j + 1; k < end; ++k) {
            uint2 ek = epad[k];
            if (ek.x == ej.x) s += __uint_as_float(ek.y);
        }
        X1[(size_t)c * NNODES + ej.x] = __float2half(s);
        if ((int)ej.x == c) dia = s;
    }
    rw[c * LWALK + 0] = dia;
}

// ---------- fp16 -> fp16 SpMM (XCD-pinned slab, diag fused) ----------
__global__ __launch_bounds__(256) void spmm_hh_k(
    const __half* __restrict__ X, __half* __restrict__ Y,
    const int* __restrict__ rowptr, const uint2* __restrict__ epad,
    float* __restrict__ rw, int kcol) {
    const int bid = blockIdx.x;
    const int slab = bid & 7;
    const int lane = threadIdx.x & 63;
    const int c =
        __builtin_amdgcn_readfirstlane((bid >> 3) * 4 + (threadIdx.x >> 6));
    const int colo = slab * 512 + lane * 8;
    const __half* Xs = X + colo;
    const int beg = rowptr[c], end = rowptr[c + 1];
    float a[8];
#pragma unroll
    for (int u = 0; u < 8; ++u) a[u] = 0.f;
    for (int e = beg; e < end; e += 8) {
        uint2 ed[8];
#pragma unroll
        for (int j = 0; j < 8; ++j) ed[j] = epad[e + j];
        uint4n x[8];
#pragma unroll
        for (int j = 0; j < 8; ++j)
            x[j] = *(const uint4n*)(Xs + (size_t)ed[j].x * NNODES);
#pragma unroll
        for (int j = 0; j < 8; ++j) {
            float v = __uint_as_float(ed[j].y);
            const __half* h = (const __half*)&x[j];
#pragma unroll
            for (int u = 0; u < 8; ++u)
                a[u] = fmaf(__half2float(h[u]), v, a[u]);
        }
    }
    if ((c >> 9) == slab && lane == ((c & 511) >> 3)) {
        float d = 0.f;
#pragma unroll
        for (int u = 0; u < 8; ++u)
            if ((c & 7) == u) d = a[u];
        rw[c * LWALK + kcol] = d;
    }
    uint4n o;
    __half2 oh[4];
#pragma unroll
    for (int u = 0; u < 4; ++u) oh[u] = __floats2half2_rn(a[2 * u], a[2 * u + 1]);
    o.x = *(unsigned int*)&oh[0];
    o.y = *(unsigned int*)&oh[1];
    o.z = *(unsigned int*)&oh[2];
    o.w = *(unsigned int*)&oh[3];
    __builtin_nontemporal_store(o, (uint4n*)(Y + (size_t)c * NNODES + colo));
}

// ---------- fp16 -> fp8 SpMM (scale by 256 on store) ----------
__global__ __launch_bounds__(256) void spmm_h8_k(
    const __half* __restrict__ X, unsigned char* __restrict__ Y8,
    const int* __restrict__ rowptr, const uint2* __restrict__ epad,
    float* __restrict__ rw, int kcol) {
    const int bid = blockIdx.x;
    const int slab = bid & 7;
    const int lane = threadIdx.x & 63;
    const int c =
        __builtin_amdgcn_readfirstlane((bid >> 3) * 4 + (threadIdx.x >> 6));
    const int colo = slab * 512 + lane * 8;
    const __half* Xs = X + colo;
    const int beg = rowptr[c], end = rowptr[c + 1];
    float a[8];
#pragma unroll
    for (int u = 0; u < 8; ++u) a[u] = 0.f;
    for (int e = beg; e < end; e += 8) {
        uint2 ed[8];
#pragma unroll
        for (int j = 0; j < 8; ++j) ed[j] = epad[e + j];
        uint4n x[8];
#pragma unroll
        for (int j = 0; j < 8; ++j)
            x[j] = *(const uint4n*)(Xs + (size_t)ed[j].x * NNODES);
#pragma unroll
        for (int j = 0; j < 8; ++j) {
            float v = __uint_as_float(ed[j].y);
            const __half* h = (const __half*)&x[j];
#pragma unroll
            for (int u = 0; u < 8; ++u)
                a[u] = fmaf(__half2float(h[u]), v, a[u]);
        }
    }
    if ((c >> 9) == slab && lane == ((c & 511) >> 3)) {
        float d = 0.f;
#pragma unroll
        for (int u = 0; u < 8; ++u)
            if ((c & 7) == u) d = a[u];
        rw[c * LWALK + kcol] = d;
    }
    float s[8];
#pragma unroll
    for (int u = 0; u < 8; ++u) s[u] = a[u] * FP8_SCALE;
    unsigned int lo, hi;
    enc8f(s, &lo, &hi);
    uint2n o;
    o.x = lo; o.y = hi;
    __builtin_nontemporal_store(o, (uint2n*)(Y8 + (size_t)c * NNODES + colo));
}

// ---------- fp8 -> fp8 SpMM (stays in scaled domain; diag unscaled) ----------
__global__ __launch_bounds__(256) void spmm_88_k(
    const unsigned char* __restrict__ X8, unsigned char* __restrict__ Y8,
    const int* __restrict__ rowptr, const uint2* __restrict__ epad,
    float* __restrict__ rw, int kcol) {
    const int bid = blockIdx.x;
    const int slab = bid & 7;
    const int lane = threadIdx.x & 63;
    const int c =
        __builtin_amdgcn_readfirstlane((bid >> 3) * 4 + (threadIdx.x >> 6));
    const int colo = slab * 512 + lane * 8;  // byte offset (fp8)
    const unsigned char* Xs = X8 + colo;
    const int beg = rowptr[c], end = rowptr[c + 1];
    float a[8];
#pragma unroll
    for (int u = 0; u < 8; ++u) a[u] = 0.f;
    for (int e = beg; e < end; e += 8) {
        uint2 ed[8];
#pragma unroll
        for (int j = 0; j < 8; ++j) ed[j] = epad[e + j];
        uint2n x[8];
#pragma unroll
        for (int j = 0; j < 8; ++j)
            x[j] = *(const uint2n*)(Xs + (size_t)ed[j].x * NNODES);
#pragma unroll
        for (int j = 0; j < 8; ++j) {
            float v = __uint_as_float(ed[j].y);
            float f[8];
            dec8f(x[j].x, x[j].y, f);
#pragma unroll
            for (int u = 0; u < 8; ++u) a[u] = fmaf(f[u], v, a[u]);
        }
    }
    if ((c >> 9) == slab && lane == ((c & 511) >> 3)) {
        float d = 0.f;
#pragma unroll
        for (int u = 0; u < 8; ++u)
            if ((c & 7) == u) d = a[u];
        rw[c * LWALK + kcol] = d * FP8_INV;
    }
    unsigned int lo, hi;
    enc8f(a, &lo, &hi);
    uint2n o;
    o.x = lo; o.y = hi;
    __builtin_nontemporal_store(o, (uint2n*)(Y8 + (size_t)c * NNODES + colo));
}

// ---------- fused paired diagonals on fp8 (scaled) matrices ----------
// rw[i,col_odd]  += (1/S^2) sum_j A[i,j] * B[j,i]
// rw[i,col_even] += (1/S^2) sum_j A[i,j] * A[j,i]
__global__ __launch_bounds__(256) void pairdiag8_k(
    const unsigned char* __restrict__ A, const unsigned char* __restrict__ B,
    float* __restrict__ rw, int col_odd, int col_even) {
    __shared__ float bt[64][65];
    __shared__ float ct[64][65];
    const int i0 = blockIdx.x * 64;
    const int t = threadIdx.x;
    const int li = t >> 2;
    const int q = t & 3;
    const int c0 = q * 16;
    const int Jbeg = blockIdx.y * (NNODES / 16);
    const int Jend = Jbeg + (NNODES / 16);
    float accO = 0.f, accE = 0.f;
    for (int J = Jbeg; J < Jend; J += 64) {
        uint4n b16 = *(const uint4n*)(B + (size_t)(J + li) * NNODES + i0 + c0);
        uint4n g16 = *(const uint4n*)(A + (size_t)(J + li) * NNODES + i0 + c0);
        __syncthreads();
        float bf[16], gf[16];
        dec8f(b16.x, b16.y, bf);
        dec8f(b16.z, b16.w, bf + 8);
        dec8f(g16.x, g16.y, gf);
        dec8f(g16.z, g16.w, gf + 8);
#pragma unroll
        for (int s = 0; s < 16; ++s) {
            bt[c0 + s][li] = bf[s];
            ct[c0 + s][li] = gf[s];
        }
        __syncthreads();
        uint4n a16 = *(const uint4n*)(A + (size_t)(i0 + li) * NNODES + J + c0);
        float af[16];
        dec8f(a16.x, a16.y, af);
        dec8f(a16.z, a16.w, af + 8);
#pragma unroll
        for (int s = 0; s < 16; ++s) {
            accO = fmaf(af[s], bt[li][c0 + s], accO);
            accE = fmaf(af[s], ct[li][c0 + s], accE);
        }
    }
    accO += __shfl_xor(accO, 1);
    accO += __shfl_xor(accO, 2);
    accE += __shfl_xor(accE, 1);
    accE += __shfl_xor(accE, 2);
    if (q == 0) {
        atomicAdd(&rw[(i0 + li) * LWALK + col_odd], accO * FP8_INV2);
        atomicAdd(&rw[(i0 + li) * LWALK + col_even], accE * FP8_INV2);
    }
}

// ---------- final linear ----------
__global__ void linear_k(const float* __restrict__ rw, const float* __restrict__ W,
                         const float* __restrict__ b, float* __restrict__ out) {
    int i = blockIdx.x * blockDim.x + threadIdx.x;
    if (i >= NNODES * ODIM) return;
    int s = i >> 3, d = i & 7;
    float acc = b[d];
#pragma unroll
    for (int k = 0; k < LWALK; ++k)
        acc = fmaf(rw[s * LWALK + k], W[d * LWALK + k], acc);
    out[i] = acc;
}

extern "C" void kernel_launch(void* const* d_in, const int* in_sizes, int n_in,
                              void* d_out, int out_size, void* d_ws, size_t ws_size,
                              hipStream_t stream) {
    const void* ei = d_in[0];
    int E = in_sizes[0] / 2;
    const float* W = (const float*)d_in[2];
    const float* bias = (const float*)d_in[3];
    float* out = (float*)d_out;

    char* ws = (char*)d_ws;
    size_t off = 0;
    auto alloc = [&](size_t bytes) -> char* {
        char* p = ws + off;
        off = (off + bytes + 255) & ~(size_t)255;
        return p;
    };
    int* flag = (int*)alloc(4);
    int* deg = (int*)alloc(NNODES * 4);
    int* cnt = (int*)alloc(NNODES * 4);
    int* rowptr = (int*)alloc((NNODES + 1) * 4);
    int* cursor = (int*)alloc(NNODES * 4);
    uint2* epad = (uint2*)alloc(((size_t)E + 8 * NNODES) * 8);
    float* rw = (float*)alloc(NNODES * LWALK * 4);
    __half* Xh = (__half*)alloc((size_t)NNODES * NNODES * 2);
    __half* Yh = (__half*)alloc((size_t)NNODES * NNODES * 2);
    unsigned char* F0 = (unsigned char*)alloc((size_t)NNODES * NNODES);
    unsigned char* F1 = (unsigned char*)alloc((size_t)NNODES * NNODES);

    (void)hipMemsetAsync(deg, 0, NNODES * 4, stream);
    (void)hipMemsetAsync(cnt, 0, NNODES * 4, stream);
    (void)hipMemsetAsync(rw, 0, NNODES * LWALK * 4, stream);
    detect_fmt_k<<<1, 64, 0, stream>>>(ei, E, flag);
    build_deg_cnt_k<<<(E + 255) / 256, 256, 0, stream>>>(ei, E, deg, cnt, flag);
    scan_k<<<1, 1024, 0, stream>>>(cnt, rowptr, cursor);
    fill_csr_k<<<(E + 255) / 256, 256, 0, stream>>>(ei, E, deg, cursor, epad, flag);
    pad_fill_k<<<(NNODES + 255) / 256, 256, 0, stream>>>(rowptr, cursor, epad);

    // X1 = P^T built directly (no spmm for m=1); diag k=1 fused.
    zero_k<<<NNODES * (NNODES / 8) / 256, 256, 0, stream>>>((uint4n*)Xh);
    x1build_k<<<(NNODES + 255) / 256, 256, 0, stream>>>(rowptr, epad, Xh, rw);

    const int SG = NNODES * 8 / 4;  // spmm grid
    dim3 pg(NNODES / 64, 16);

    spmm_hh_k<<<SG, 256, 0, stream>>>(Xh, Yh, rowptr, epad, rw, 1);   // X2
    spmm_hh_k<<<SG, 256, 0, stream>>>(Yh, Xh, rowptr, epad, rw, 2);   // X3
    spmm_h8_k<<<SG, 256, 0, stream>>>(Xh, F0, rowptr, epad, rw, 3);   // X4 (fp8)
    spmm_88_k<<<SG, 256, 0, stream>>>(F0, F1, rowptr, epad, rw, 4);   // X5
    pairdiag8_k<<<pg, 256, 0, stream>>>(F1, F0, rw, 8, 9);            // k=9,10
    spmm_88_k<<<SG, 256, 0, stream>>>(F1, F0, rowptr, epad, rw, 5);   // X6
    pairdiag8_k<<<pg, 256, 0, stream>>>(F0, F1, rw, 10, 11);          // k=11,12
    spmm_88_k<<<SG, 256, 0, stream>>>(F0, F1, rowptr, epad, rw, 6);   // X7
    pairdiag8_k<<<pg, 256, 0, stream>>>(F1, F0, rw, 12, 13);          // k=13,14
    spmm_88_k<<<SG, 256, 0, stream>>>(F1, F0, rowptr, epad, rw, 7);   // X8
    pairdiag8_k<<<pg, 256, 0, stream>>>(F0, F1, rw, 14, 15);          // k=15,16

    linear_k<<<(NNODES * ODIM + 255) / 256, 256, 0, stream>>>(rw, W, bias, out);
}

// Round 9
// 352.876 us; speedup vs baseline: 1.3620x; 1.3620x over previous
//
#include <hip/hip_runtime.h>
#include <hip/hip_fp16.h>
#include <hip/hip_fp8.h>

#define NNODES 4096
#define LWALK 16
#define ODIM 8

#define FP8_SCALE 256.0f
#define FP8_INV   0.00390625f          // 1/256
#define FP8_INV2  1.52587890625e-05f   // 1/65536

typedef unsigned int uint4n __attribute__((ext_vector_type(4)));
typedef unsigned int uint2n __attribute__((ext_vector_type(2)));
typedef float float2n __attribute__((ext_vector_type(2)));

// ---------- fp8 helpers (HW cvt; format-internal-consistency is all we need) ----
__device__ __forceinline__ void dec8f(unsigned int lo, unsigned int hi, float* f) {
#if __has_builtin(__builtin_amdgcn_cvt_pk_f32_fp8)
    float2n p;
    p = __builtin_amdgcn_cvt_pk_f32_fp8((int)lo, false); f[0] = p.x; f[1] = p.y;
    p = __builtin_amdgcn_cvt_pk_f32_fp8((int)lo, true);  f[2] = p.x; f[3] = p.y;
    p = __builtin_amdgcn_cvt_pk_f32_fp8((int)hi, false); f[4] = p.x; f[5] = p.y;
    p = __builtin_amdgcn_cvt_pk_f32_fp8((int)hi, true);  f[6] = p.x; f[7] = p.y;
#else
    unsigned int w[2] = {lo, hi};
    const unsigned char* b = (const unsigned char*)w;
#pragma unroll
    for (int i = 0; i < 8; ++i) {
        __hip_fp8_e4m3 t; t.__x = b[i]; f[i] = (float)t;
    }
#endif
}

__device__ __forceinline__ void enc8f(const float* a, unsigned int* lo,
                                      unsigned int* hi) {
#if __has_builtin(__builtin_amdgcn_cvt_pk_fp8_f32)
    int l = 0, h = 0;
    l = __builtin_amdgcn_cvt_pk_fp8_f32(a[0], a[1], l, false);
    l = __builtin_amdgcn_cvt_pk_fp8_f32(a[2], a[3], l, true);
    h = __builtin_amdgcn_cvt_pk_fp8_f32(a[4], a[5], h, false);
    h = __builtin_amdgcn_cvt_pk_fp8_f32(a[6], a[7], h, true);
    *lo = (unsigned int)l; *hi = (unsigned int)h;
#else
    unsigned char b[8];
#pragma unroll
    for (int i = 0; i < 8; ++i)
        b[i] = __hip_cvt_float_to_fp8(a[i], __HIP_SATFINITE, __HIP_E4M3);
    unsigned int w[2];
    __builtin_memcpy(w, b, 8);
    *lo = w[0]; *hi = w[1];
#endif
}

// ---------- edge-index dtype detection (int32 vs int64 on device) ----------
__global__ void detect_fmt_k(const void* ei, int E, int* flag) {
    if (blockIdx.x == 0 && threadIdx.x == 0) {
        const long long* p = (const long long*)ei;
        int ok = 1;
        for (int i = 0; i < 64; ++i) {
            long long v = p[i];
            if (v < 0 || v >= NNODES) { ok = 0; break; }
        }
        *flag = ok;  // 1 => int64 layout, 0 => int32 layout
    }
}

__device__ __forceinline__ int load_idx(const void* p, int i, int fmt) {
    if (fmt) return (int)((const long long*)p)[i];
    return ((const int*)p)[i];
}

// ---------- degree + in-degree counts ----------
__global__ void build_deg_cnt_k(const void* ei, int E, int* deg, int* cnt,
                                const int* fmt) {
    int e = blockIdx.x * blockDim.x + threadIdx.x;
    if (e >= E) return;
    int f = *fmt;
    int r = load_idx(ei, e, f);
    int c = load_idx(ei, E + e, f);
    atomicAdd(&deg[r], 1);
    atomicAdd(&cnt[c], 1);
}

// ---------- exclusive scan over padded (multiple-of-8) counts ----------
__global__ void scan_k(const int* __restrict__ cnt, int* __restrict__ rowptr,
                       int* __restrict__ cursor) {
    __shared__ int sm[1024];
    int tid = threadIdx.x;
    int v0 = (cnt[4 * tid + 0] + 7) & ~7;
    int v1 = (cnt[4 * tid + 1] + 7) & ~7;
    int v2 = (cnt[4 * tid + 2] + 7) & ~7;
    int v3 = (cnt[4 * tid + 3] + 7) & ~7;
    int tsum = v0 + v1 + v2 + v3;
    sm[tid] = tsum;
    __syncthreads();
    int val = tsum;
    for (int off = 1; off < 1024; off <<= 1) {
        int t = (tid >= off) ? sm[tid - off] : 0;
        __syncthreads();
        val += t;
        sm[tid] = val;
        __syncthreads();
    }
    int excl = val - tsum;
    int p0 = excl, p1 = excl + v0, p2 = p1 + v1, p3 = p2 + v2;
    rowptr[4 * tid + 0] = p0; rowptr[4 * tid + 1] = p1;
    rowptr[4 * tid + 2] = p2; rowptr[4 * tid + 3] = p3;
    cursor[4 * tid + 0] = p0; cursor[4 * tid + 1] = p1;
    cursor[4 * tid + 2] = p2; cursor[4 * tid + 3] = p3;
    if (tid == 1023) rowptr[4096] = val;
}

// ---------- counting-sort fill of interleaved padded column-CSR ----------
__global__ void fill_csr_k(const void* ei, int E, const int* __restrict__ deg,
                           int* cursor, uint2* __restrict__ epad, const int* fmt) {
    int e = blockIdx.x * blockDim.x + threadIdx.x;
    if (e >= E) return;
    int f = *fmt;
    int r = load_idx(ei, e, f);
    int c = load_idx(ei, E + e, f);
    int pos = atomicAdd(&cursor[c], 1);
    int d = deg[r];
    float v = 1.0f / (float)(d < 1 ? 1 : d);
    epad[pos] = make_uint2((unsigned)r, __float_as_uint(v));
}

// ---------- zero-fill the padding slots (r=0, v=0 -> harmless) ----------
__global__ void pad_fill_k(const int* __restrict__ rowptr,
                           const int* __restrict__ cursor,
                           uint2* __restrict__ epad) {
    int c = blockIdx.x * blockDim.x + threadIdx.x;
    if (c >= NNODES) return;
    for (int p = cursor[c]; p < rowptr[c + 1]; ++p)
        epad[p] = make_uint2(0u, 0u);
}

// ---------- zero an fp16 buffer ----------
__global__ void zero_k(uint4n* p) {
    int i = blockIdx.x * blockDim.x + threadIdx.x;
    uint4n z = {0u, 0u, 0u, 0u};
    p[i] = z;
}

// ---------- X1 = P^T via parallel scatter (CAS fp16 add; dups combine) ----------
__global__ void x1scatter_k(const void* ei, int E, const int* __restrict__ deg,
                            __half* __restrict__ X1, const int* fmt) {
    int e = blockIdx.x * blockDim.x + threadIdx.x;
    if (e >= E) return;
    int f = *fmt;
    int r = load_idx(ei, e, f);
    int c = load_idx(ei, E + e, f);
    int d = deg[r];
    float v = 1.0f / (float)(d < 1 ? 1 : d);
    size_t idx = (size_t)c * NNODES + r;
    unsigned int* base = (unsigned int*)(X1 + (idx & ~(size_t)1));
    bool hi = (idx & 1) != 0;
    unsigned int old = *base, assumed;
    do {
        assumed = old;
        unsigned short cur = hi ? (unsigned short)(assumed >> 16)
                                : (unsigned short)(assumed & 0xFFFFu);
        float nf = __half2float(__ushort_as_half(cur)) + v;
        unsigned short ns = __half_as_ushort(__float2half(nf));
        unsigned int nv = hi ? ((assumed & 0x0000FFFFu) | ((unsigned int)ns << 16))
                             : ((assumed & 0xFFFF0000u) | ns);
        old = atomicCAS(base, assumed, nv);
    } while (old != assumed);
}

// ---------- diag k=1 read ----------
__global__ void diag1_k(const __half* __restrict__ X1, float* __restrict__ rw) {
    int i = blockIdx.x * blockDim.x + threadIdx.x;
    if (i < NNODES)
        rw[i * LWALK + 0] = __half2float(X1[(size_t)i * NNODES + i]);
}

// ---------- fp16 -> fp16 SpMM (XCD-pinned slab, diag fused) ----------
__global__ __launch_bounds__(256) void spmm_hh_k(
    const __half* __restrict__ X, __half* __restrict__ Y,
    const int* __restrict__ rowptr, const uint2* __restrict__ epad,
    float* __restrict__ rw, int kcol) {
    const int bid = blockIdx.x;
    const int slab = bid & 7;
    const int lane = threadIdx.x & 63;
    const int c =
        __builtin_amdgcn_readfirstlane((bid >> 3) * 4 + (threadIdx.x >> 6));
    const int colo = slab * 512 + lane * 8;
    const __half* Xs = X + colo;
    const int beg = rowptr[c], end = rowptr[c + 1];
    float a[8];
#pragma unroll
    for (int u = 0; u < 8; ++u) a[u] = 0.f;
    for (int e = beg; e < end; e += 8) {
        uint2 ed[8];
#pragma unroll
        for (int j = 0; j < 8; ++j) ed[j] = epad[e + j];
        uint4n x[8];
#pragma unroll
        for (int j = 0; j < 8; ++j)
            x[j] = *(const uint4n*)(Xs + (size_t)ed[j].x * NNODES);
#pragma unroll
        for (int j = 0; j < 8; ++j) {
            float v = __uint_as_float(ed[j].y);
            const __half* h = (const __half*)&x[j];
#pragma unroll
            for (int u = 0; u < 8; ++u)
                a[u] = fmaf(__half2float(h[u]), v, a[u]);
        }
    }
    if ((c >> 9) == slab && lane == ((c & 511) >> 3)) {
        float d = 0.f;
#pragma unroll
        for (int u = 0; u < 8; ++u)
            if ((c & 7) == u) d = a[u];
        rw[c * LWALK + kcol] = d;
    }
    uint4n o;
    __half2 oh[4];
#pragma unroll
    for (int u = 0; u < 4; ++u) oh[u] = __floats2half2_rn(a[2 * u], a[2 * u + 1]);
    o.x = *(unsigned int*)&oh[0];
    o.y = *(unsigned int*)&oh[1];
    o.z = *(unsigned int*)&oh[2];
    o.w = *(unsigned int*)&oh[3];
    __builtin_nontemporal_store(o, (uint4n*)(Y + (size_t)c * NNODES + colo));
}

// ---------- fp16 -> fp8 SpMM (scale by 256 on store) ----------
__global__ __launch_bounds__(256) void spmm_h8_k(
    const __half* __restrict__ X, unsigned char* __restrict__ Y8,
    const int* __restrict__ rowptr, const uint2* __restrict__ epad,
    float* __restrict__ rw, int kcol) {
    const int bid = blockIdx.x;
    const int slab = bid & 7;
    const int lane = threadIdx.x & 63;
    const int c =
        __builtin_amdgcn_readfirstlane((bid >> 3) * 4 + (threadIdx.x >> 6));
    const int colo = slab * 512 + lane * 8;
    const __half* Xs = X + colo;
    const int beg = rowptr[c], end = rowptr[c + 1];
    float a[8];
#pragma unroll
    for (int u = 0; u < 8; ++u) a[u] = 0.f;
    for (int e = beg; e < end; e += 8) {
        uint2 ed[8];
#pragma unroll
        for (int j = 0; j < 8; ++j) ed[j] = epad[e + j];
        uint4n x[8];
#pragma unroll
        for (int j = 0; j < 8; ++j)
            x[j] = *(const uint4n*)(Xs + (size_t)ed[j].x * NNODES);
#pragma unroll
        for (int j = 0; j < 8; ++j) {
            float v = __uint_as_float(ed[j].y);
            const __half* h = (const __half*)&x[j];
#pragma unroll
            for (int u = 0; u < 8; ++u)
                a[u] = fmaf(__half2float(h[u]), v, a[u]);
        }
    }
    if ((c >> 9) == slab && lane == ((c & 511) >> 3)) {
        float d = 0.f;
#pragma unroll
        for (int u = 0; u < 8; ++u)
            if ((c & 7) == u) d = a[u];
        rw[c * LWALK + kcol] = d;
    }
    float s[8];
#pragma unroll
    for (int u = 0; u < 8; ++u) s[u] = a[u] * FP8_SCALE;
    unsigned int lo, hi;
    enc8f(s, &lo, &hi);
    uint2n o;
    o.x = lo; o.y = hi;
    __builtin_nontemporal_store(o, (uint2n*)(Y8 + (size_t)c * NNODES + colo));
}

// ---------- fp8 -> fp8 SpMM (stays in scaled domain; diag unscaled) ----------
__global__ __launch_bounds__(256) void spmm_88_k(
    const unsigned char* __restrict__ X8, unsigned char* __restrict__ Y8,
    const int* __restrict__ rowptr, const uint2* __restrict__ epad,
    float* __restrict__ rw, int kcol) {
    const int bid = blockIdx.x;
    const int slab = bid & 7;
    const int lane = threadIdx.x & 63;
    const int c =
        __builtin_amdgcn_readfirstlane((bid >> 3) * 4 + (threadIdx.x >> 6));
    const int colo = slab * 512 + lane * 8;  // byte offset (fp8)
    const unsigned char* Xs = X8 + colo;
    const int beg = rowptr[c], end = rowptr[c + 1];
    float a[8];
#pragma unroll
    for (int u = 0; u < 8; ++u) a[u] = 0.f;
    for (int e = beg; e < end; e += 8) {
        uint2 ed[8];
#pragma unroll
        for (int j = 0; j < 8; ++j) ed[j] = epad[e + j];
        uint2n x[8];
#pragma unroll
        for (int j = 0; j < 8; ++j)
            x[j] = *(const uint2n*)(Xs + (size_t)ed[j].x * NNODES);
#pragma unroll
        for (int j = 0; j < 8; ++j) {
            float v = __uint_as_float(ed[j].y);
            float f[8];
            dec8f(x[j].x, x[j].y, f);
#pragma unroll
            for (int u = 0; u < 8; ++u) a[u] = fmaf(f[u], v, a[u]);
        }
    }
    if ((c >> 9) == slab && lane == ((c & 511) >> 3)) {
        float d = 0.f;
#pragma unroll
        for (int u = 0; u < 8; ++u)
            if ((c & 7) == u) d = a[u];
        rw[c * LWALK + kcol] = d * FP8_INV;
    }
    unsigned int lo, hi;
    enc8f(a, &lo, &hi);
    uint2n o;
    o.x = lo; o.y = hi;
    __builtin_nontemporal_store(o, (uint2n*)(Y8 + (size_t)c * NNODES + colo));
}

// ---------- fused paired diagonals on fp8 (scaled) matrices ----------
__global__ __launch_bounds__(256) void pairdiag8_k(
    const unsigned char* __restrict__ A, const unsigned char* __restrict__ B,
    float* __restrict__ rw, int col_odd, int col_even) {
    __shared__ float bt[64][65];
    __shared__ float ct[64][65];
    const int i0 = blockIdx.x * 64;
    const int t = threadIdx.x;
    const int li = t >> 2;
    const int q = t & 3;
    const int c0 = q * 16;
    const int Jbeg = blockIdx.y * (NNODES / 16);
    const int Jend = Jbeg + (NNODES / 16);
    float accO = 0.f, accE = 0.f;
    for (int J = Jbeg; J < Jend; J += 64) {
        uint4n b16 = *(const uint4n*)(B + (size_t)(J + li) * NNODES + i0 + c0);
        uint4n g16 = *(const uint4n*)(A + (size_t)(J + li) * NNODES + i0 + c0);
        __syncthreads();
        float bf[16], gf[16];
        dec8f(b16.x, b16.y, bf);
        dec8f(b16.z, b16.w, bf + 8);
        dec8f(g16.x, g16.y, gf);
        dec8f(g16.z, g16.w, gf + 8);
#pragma unroll
        for (int s = 0; s < 16; ++s) {
            bt[c0 + s][li] = bf[s];
            ct[c0 + s][li] = gf[s];
        }
        __syncthreads();
        uint4n a16 = *(const uint4n*)(A + (size_t)(i0 + li) * NNODES + J + c0);
        float af[16];
        dec8f(a16.x, a16.y, af);
        dec8f(a16.z, a16.w, af + 8);
#pragma unroll
        for (int s = 0; s < 16; ++s) {
            accO = fmaf(af[s], bt[li][c0 + s], accO);
            accE = fmaf(af[s], ct[li][c0 + s], accE);
        }
    }
    accO += __shfl_xor(accO, 1);
    accO += __shfl_xor(accO, 2);
    accE += __shfl_xor(accE, 1);
    accE += __shfl_xor(accE, 2);
    if (q == 0) {
        atomicAdd(&rw[(i0 + li) * LWALK + col_odd], accO * FP8_INV2);
        atomicAdd(&rw[(i0 + li) * LWALK + col_even], accE * FP8_INV2);
    }
}

// ---------- final linear ----------
__global__ void linear_k(const float* __restrict__ rw, const float* __restrict__ W,
                         const float* __restrict__ b, float* __restrict__ out) {
    int i = blockIdx.x * blockDim.x + threadIdx.x;
    if (i >= NNODES * ODIM) return;
    int s = i >> 3, d = i & 7;
    float acc = b[d];
#pragma unroll
    for (int k = 0; k < LWALK; ++k)
        acc = fmaf(rw[s * LWALK + k], W[d * LWALK + k], acc);
    out[i] = acc;
}

extern "C" void kernel_launch(void* const* d_in, const int* in_sizes, int n_in,
                              void* d_out, int out_size, void* d_ws, size_t ws_size,
                              hipStream_t stream) {
    const void* ei = d_in[0];
    int E = in_sizes[0] / 2;
    const float* W = (const float*)d_in[2];
    const float* bias = (const float*)d_in[3];
    float* out = (float*)d_out;

    char* ws = (char*)d_ws;
    size_t off = 0;
    auto alloc = [&](size_t bytes) -> char* {
        char* p = ws + off;
        off = (off + bytes + 255) & ~(size_t)255;
        return p;
    };
    int* flag = (int*)alloc(4);
    int* deg = (int*)alloc(NNODES * 4);
    int* cnt = (int*)alloc(NNODES * 4);
    int* rowptr = (int*)alloc((NNODES + 1) * 4);
    int* cursor = (int*)alloc(NNODES * 4);
    uint2* epad = (uint2*)alloc(((size_t)E + 8 * NNODES) * 8);
    float* rw = (float*)alloc(NNODES * LWALK * 4);
    __half* Xh = (__half*)alloc((size_t)NNODES * NNODES * 2);
    __half* Yh = (__half*)alloc((size_t)NNODES * NNODES * 2);
    unsigned char* F0 = (unsigned char*)alloc((size_t)NNODES * NNODES);
    unsigned char* F1 = (unsigned char*)alloc((size_t)NNODES * NNODES);

    (void)hipMemsetAsync(deg, 0, NNODES * 4, stream);
    (void)hipMemsetAsync(cnt, 0, NNODES * 4, stream);
    (void)hipMemsetAsync(rw, 0, NNODES * LWALK * 4, stream);
    detect_fmt_k<<<1, 64, 0, stream>>>(ei, E, flag);
    build_deg_cnt_k<<<(E + 255) / 256, 256, 0, stream>>>(ei, E, deg, cnt, flag);
    scan_k<<<1, 1024, 0, stream>>>(cnt, rowptr, cursor);
    fill_csr_k<<<(E + 255) / 256, 256, 0, stream>>>(ei, E, deg, cursor, epad, flag);
    pad_fill_k<<<(NNODES + 255) / 256, 256, 0, stream>>>(rowptr, cursor, epad);

    // X1 = P^T via zero + parallel scatter; diag k=1 separate tiny kernel.
    zero_k<<<NNODES * (NNODES / 8) / 256, 256, 0, stream>>>((uint4n*)Xh);
    x1scatter_k<<<(E + 255) / 256, 256, 0, stream>>>(ei, E, deg, Xh, flag);
    diag1_k<<<(NNODES + 255) / 256, 256, 0, stream>>>(Xh, rw);

    const int SG = NNODES * 8 / 4;  // spmm grid
    dim3 pg(NNODES / 64, 16);

    spmm_hh_k<<<SG, 256, 0, stream>>>(Xh, Yh, rowptr, epad, rw, 1);   // X2 (fp16)
    spmm_h8_k<<<SG, 256, 0, stream>>>(Yh, F0, rowptr, epad, rw, 2);   // X3 (fp8)
    spmm_88_k<<<SG, 256, 0, stream>>>(F0, F1, rowptr, epad, rw, 3);   // X4
    spmm_88_k<<<SG, 256, 0, stream>>>(F1, F0, rowptr, epad, rw, 4);   // X5
    pairdiag8_k<<<pg, 256, 0, stream>>>(F0, F1, rw, 8, 9);            // k=9,10
    spmm_88_k<<<SG, 256, 0, stream>>>(F0, F1, rowptr, epad, rw, 5);   // X6
    pairdiag8_k<<<pg, 256, 0, stream>>>(F1, F0, rw, 10, 11);          // k=11,12
    spmm_88_k<<<SG, 256, 0, stream>>>(F1, F0, rowptr, epad, rw, 6);   // X7
    pairdiag8_k<<<pg, 256, 0, stream>>>(F0, F1, rw, 12, 13);          // k=13,14
    spmm_88_k<<<SG, 256, 0, stream>>>(F0, F1, rowptr, epad, rw, 7);   // X8
    pairdiag8_k<<<pg, 256, 0, stream>>>(F1, F0, rw, 14, 15);          // k=15,16

    linear_k<<<(NNODES * ODIM + 255) / 256, 256, 0, stream>>>(rw, W, bias, out);
}

// Round 10
// 322.744 us; speedup vs baseline: 1.4892x; 1.0934x over previous
//
#include <hip/hip_runtime.h>
#include <hip/hip_fp16.h>
#include <hip/hip_fp8.h>

#define NNODES 4096
#define LWALK 16
#define ODIM 8

#define FP8_SCALE 256.0f
#define FP8_INV   0.00390625f          // 1/256
#define FP8_INV2  1.52587890625e-05f   // 1/65536

typedef unsigned int uint4n __attribute__((ext_vector_type(4)));
typedef unsigned int uint2n __attribute__((ext_vector_type(2)));
typedef float float2n __attribute__((ext_vector_type(2)));

// ---------- fp8 helpers ----------
__device__ __forceinline__ void dec8f(unsigned int lo, unsigned int hi, float* f) {
#if __has_builtin(__builtin_amdgcn_cvt_pk_f32_fp8)
    float2n p;
    p = __builtin_amdgcn_cvt_pk_f32_fp8((int)lo, false); f[0] = p.x; f[1] = p.y;
    p = __builtin_amdgcn_cvt_pk_f32_fp8((int)lo, true);  f[2] = p.x; f[3] = p.y;
    p = __builtin_amdgcn_cvt_pk_f32_fp8((int)hi, false); f[4] = p.x; f[5] = p.y;
    p = __builtin_amdgcn_cvt_pk_f32_fp8((int)hi, true);  f[6] = p.x; f[7] = p.y;
#else
    unsigned int w[2] = {lo, hi};
    const unsigned char* b = (const unsigned char*)w;
#pragma unroll
    for (int i = 0; i < 8; ++i) {
        __hip_fp8_e4m3 t; t.__x = b[i]; f[i] = (float)t;
    }
#endif
}

__device__ __forceinline__ void enc8f(const float* a, unsigned int* lo,
                                      unsigned int* hi) {
#if __has_builtin(__builtin_amdgcn_cvt_pk_fp8_f32)
    int l = 0, h = 0;
    l = __builtin_amdgcn_cvt_pk_fp8_f32(a[0], a[1], l, false);
    l = __builtin_amdgcn_cvt_pk_fp8_f32(a[2], a[3], l, true);
    h = __builtin_amdgcn_cvt_pk_fp8_f32(a[4], a[5], h, false);
    h = __builtin_amdgcn_cvt_pk_fp8_f32(a[6], a[7], h, true);
    *lo = (unsigned int)l; *hi = (unsigned int)h;
#else
    unsigned char b[8];
#pragma unroll
    for (int i = 0; i < 8; ++i)
        b[i] = __hip_cvt_float_to_fp8(a[i], __HIP_SATFINITE, __HIP_E4M3);
    unsigned int w[2];
    __builtin_memcpy(w, b, 8);
    *lo = w[0]; *hi = w[1];
#endif
}

__device__ __forceinline__ void dec16f(uint4n w, float* f) {
    dec8f(w.x, w.y, f);
    dec8f(w.z, w.w, f + 8);
}

__device__ __forceinline__ uint4n enc16f(const float* a) {
    uint4n o;
    unsigned int lo, hi;
    enc8f(a, &lo, &hi);     o.x = lo; o.y = hi;
    enc8f(a + 8, &lo, &hi); o.z = lo; o.w = hi;
    return o;
}

// ---------- edge-index dtype detection ----------
__global__ void detect_fmt_k(const void* ei, int E, int* flag) {
    if (blockIdx.x == 0 && threadIdx.x == 0) {
        const long long* p = (const long long*)ei;
        int ok = 1;
        for (int i = 0; i < 64; ++i) {
            long long v = p[i];
            if (v < 0 || v >= NNODES) { ok = 0; break; }
        }
        *flag = ok;
    }
}

__device__ __forceinline__ int load_idx(const void* p, int i, int fmt) {
    if (fmt) return (int)((const long long*)p)[i];
    return ((const int*)p)[i];
}

__global__ void build_deg_cnt_k(const void* ei, int E, int* deg, int* cnt,
                                const int* fmt) {
    int e = blockIdx.x * blockDim.x + threadIdx.x;
    if (e >= E) return;
    int f = *fmt;
    int r = load_idx(ei, e, f);
    int c = load_idx(ei, E + e, f);
    atomicAdd(&deg[r], 1);
    atomicAdd(&cnt[c], 1);
}

__global__ void scan_k(const int* __restrict__ cnt, int* __restrict__ rowptr,
                       int* __restrict__ cursor) {
    __shared__ int sm[1024];
    int tid = threadIdx.x;
    int v0 = (cnt[4 * tid + 0] + 7) & ~7;
    int v1 = (cnt[4 * tid + 1] + 7) & ~7;
    int v2 = (cnt[4 * tid + 2] + 7) & ~7;
    int v3 = (cnt[4 * tid + 3] + 7) & ~7;
    int tsum = v0 + v1 + v2 + v3;
    sm[tid] = tsum;
    __syncthreads();
    int val = tsum;
    for (int off = 1; off < 1024; off <<= 1) {
        int t = (tid >= off) ? sm[tid - off] : 0;
        __syncthreads();
        val += t;
        sm[tid] = val;
        __syncthreads();
    }
    int excl = val - tsum;
    int p0 = excl, p1 = excl + v0, p2 = p1 + v1, p3 = p2 + v2;
    rowptr[4 * tid + 0] = p0; rowptr[4 * tid + 1] = p1;
    rowptr[4 * tid + 2] = p2; rowptr[4 * tid + 3] = p3;
    cursor[4 * tid + 0] = p0; cursor[4 * tid + 1] = p1;
    cursor[4 * tid + 2] = p2; cursor[4 * tid + 3] = p3;
    if (tid == 1023) rowptr[4096] = val;
}

__global__ void fill_csr_k(const void* ei, int E, const int* __restrict__ deg,
                           int* cursor, uint2* __restrict__ epad, const int* fmt) {
    int e = blockIdx.x * blockDim.x + threadIdx.x;
    if (e >= E) return;
    int f = *fmt;
    int r = load_idx(ei, e, f);
    int c = load_idx(ei, E + e, f);
    int pos = atomicAdd(&cursor[c], 1);
    int d = deg[r];
    float v = 1.0f / (float)(d < 1 ? 1 : d);
    epad[pos] = make_uint2((unsigned)r, __float_as_uint(v));
}

__global__ void pad_fill_k(const int* __restrict__ rowptr,
                           const int* __restrict__ cursor,
                           uint2* __restrict__ epad) {
    int c = blockIdx.x * blockDim.x + threadIdx.x;
    if (c >= NNODES) return;
    for (int p = cursor[c]; p < rowptr[c + 1]; ++p)
        epad[p] = make_uint2(0u, 0u);
}

__global__ void zero_k(uint4n* p) {
    int i = blockIdx.x * blockDim.x + threadIdx.x;
    uint4n z = {0u, 0u, 0u, 0u};
    p[i] = z;
}

// ---------- X1 = P^T via parallel scatter (CAS fp16 add; dups combine) ----------
__global__ void x1scatter_k(const void* ei, int E, const int* __restrict__ deg,
                            __half* __restrict__ X1, const int* fmt) {
    int e = blockIdx.x * blockDim.x + threadIdx.x;
    if (e >= E) return;
    int f = *fmt;
    int r = load_idx(ei, e, f);
    int c = load_idx(ei, E + e, f);
    int d = deg[r];
    float v = 1.0f / (float)(d < 1 ? 1 : d);
    size_t idx = (size_t)c * NNODES + r;
    unsigned int* base = (unsigned int*)(X1 + (idx & ~(size_t)1));
    bool hi = (idx & 1) != 0;
    unsigned int old = *base, assumed;
    do {
        assumed = old;
        unsigned short cur = hi ? (unsigned short)(assumed >> 16)
                                : (unsigned short)(assumed & 0xFFFFu);
        float nf = __half2float(__ushort_as_half(cur)) + v;
        unsigned short ns = __half_as_ushort(__float2half(nf));
        unsigned int nv = hi ? ((assumed & 0x0000FFFFu) | ((unsigned int)ns << 16))
                             : ((assumed & 0xFFFF0000u) | ns);
        old = atomicCAS(base, assumed, nv);
    } while (old != assumed);
}

// ---------- L1: fp16 X1 -> fp8 X2 SpMM; diag k=1 (input) + k=2 (output) -------
__global__ __launch_bounds__(256) void spmm_h8_k(
    const __half* __restrict__ X, unsigned char* __restrict__ Y8,
    const int* __restrict__ rowptr, const uint2* __restrict__ epad,
    float* __restrict__ rw) {
    const int bid = blockIdx.x;          // 8192 blocks x 4 waves
    const int slab = bid & 7;            // 512-col fp16 slabs, XCD-pinned
    const int lane = threadIdx.x & 63;
    const int c =
        __builtin_amdgcn_readfirstlane((bid >> 3) * 4 + (threadIdx.x >> 6));
    const int colo = slab * 512 + lane * 8;
    const __half* Xs = X + colo;
    const int beg = rowptr[c], end = rowptr[c + 1];
    float a[8];
#pragma unroll
    for (int u = 0; u < 8; ++u) a[u] = 0.f;
    for (int e = beg; e < end; e += 8) {
        uint2 ed[8];
#pragma unroll
        for (int j = 0; j < 8; ++j) ed[j] = epad[e + j];
        uint4n x[8];
#pragma unroll
        for (int j = 0; j < 8; ++j)
            x[j] = *(const uint4n*)(Xs + (size_t)ed[j].x * NNODES);
#pragma unroll
        for (int j = 0; j < 8; ++j) {
            float v = __uint_as_float(ed[j].y);
            const __half* h = (const __half*)&x[j];
#pragma unroll
            for (int u = 0; u < 8; ++u)
                a[u] = fmaf(__half2float(h[u]), v, a[u]);
        }
    }
    if ((c >> 9) == slab && lane == ((c & 511) >> 3)) {
        // diag k=1 from input, k=2 from accumulator (pre-rounding)
        rw[c * LWALK + 0] = __half2float(X[(size_t)c * NNODES + c]);
        float d = 0.f;
#pragma unroll
        for (int u = 0; u < 8; ++u)
            if ((c & 7) == u) d = a[u];
        rw[c * LWALK + 1] = d;
    }
    float s[8];
#pragma unroll
    for (int u = 0; u < 8; ++u) s[u] = a[u] * FP8_SCALE;
    unsigned int lo, hi;
    enc8f(s, &lo, &hi);
    uint2n o;
    o.x = lo; o.y = hi;
    __builtin_nontemporal_store(o, (uint2n*)(Y8 + (size_t)c * NNODES + colo));
}

// ---------- fused fp8 SpMM (+optional pairdiag in appended blocks) ----------
// spmm blocks (bid < nspmm=4096): wave-per-(c,slab), 1024-col fp8 slabs,
//   slab = bid&3 -> slab s pinned to XCDs {s, s+4} (4MB slab = one L2).
// pair blocks (bid >= nspmm): rw[:,colO] += (1/S^2) sum_j A[i,j]B[j,i],
//   rw[:,colE] += (1/S^2) sum_j A[i,j]A[j,i]; non-temporal loads.
__global__ __launch_bounds__(256) void fused8_k(
    const unsigned char* __restrict__ X8, unsigned char* __restrict__ Y8,
    const int* __restrict__ rowptr, const uint2* __restrict__ epad,
    float* __restrict__ rw, int kcol,
    const unsigned char* __restrict__ PA, const unsigned char* __restrict__ PB,
    int colO, int colE, int nspmm) {
    __shared__ __half bt[64][66];
    __shared__ __half ct[64][66];
    const int bid = blockIdx.x;
    if (bid < nspmm) {
        const int slab = bid & 3;
        const int lane = threadIdx.x & 63;
        const int c =
            __builtin_amdgcn_readfirstlane((bid >> 2) * 4 + (threadIdx.x >> 6));
        const int colo = slab * 1024 + lane * 16;  // fp8 byte offset
        const unsigned char* Xs = X8 + colo;
        const int beg = rowptr[c], end = rowptr[c + 1];
        float a[16];
#pragma unroll
        for (int u = 0; u < 16; ++u) a[u] = 0.f;
        for (int e = beg; e < end; e += 8) {
            uint2 ed[8];
#pragma unroll
            for (int j = 0; j < 8; ++j) ed[j] = epad[e + j];
            uint4n x[8];
#pragma unroll
            for (int j = 0; j < 8; ++j)
                x[j] = *(const uint4n*)(Xs + (size_t)ed[j].x * NNODES);
#pragma unroll
            for (int j = 0; j < 8; ++j) {
                float v = __uint_as_float(ed[j].y);
                float f[16];
                dec16f(x[j], f);
#pragma unroll
                for (int u = 0; u < 16; ++u) a[u] = fmaf(f[u], v, a[u]);
            }
        }
        if ((c >> 10) == slab && lane == ((c & 1023) >> 4)) {
            float d = 0.f;
#pragma unroll
            for (int u = 0; u < 16; ++u)
                if ((c & 15) == u) d = a[u];
            rw[c * LWALK + kcol] = d * FP8_INV;
        }
        uint4n o = enc16f(a);
        __builtin_nontemporal_store(o, (uint4n*)(Y8 + (size_t)c * NNODES + colo));
    } else {
        const int pb = bid - nspmm;      // 1024 pair blocks
        const int i0 = (pb & 63) * 64;
        const int Jbeg = (pb >> 6) * (NNODES / 16);
        const int Jend = Jbeg + (NNODES / 16);
        const int t = threadIdx.x;
        const int li = t >> 2;
        const int q = t & 3;
        const int c0 = q * 16;
        float accO = 0.f, accE = 0.f;
        for (int J = Jbeg; J < Jend; J += 64) {
            uint4n b16 = __builtin_nontemporal_load(
                (const uint4n*)(PB + (size_t)(J + li) * NNODES + i0 + c0));
            uint4n g16 = __builtin_nontemporal_load(
                (const uint4n*)(PA + (size_t)(J + li) * NNODES + i0 + c0));
            __syncthreads();
            float bf[16], gf[16];
            dec16f(b16, bf);
            dec16f(g16, gf);
#pragma unroll
            for (int s = 0; s < 16; ++s) {
                bt[c0 + s][li] = __float2half(bf[s]);  // fp8 values exact in fp16
                ct[c0 + s][li] = __float2half(gf[s]);
            }
            __syncthreads();
            uint4n a16 = __builtin_nontemporal_load(
                (const uint4n*)(PA + (size_t)(i0 + li) * NNODES + J + c0));
            float af[16];
            dec16f(a16, af);
#pragma unroll
            for (int s = 0; s < 16; ++s) {
                accO = fmaf(af[s], __half2float(bt[li][c0 + s]), accO);
                accE = fmaf(af[s], __half2float(ct[li][c0 + s]), accE);
            }
        }
        accO += __shfl_xor(accO, 1);
        accO += __shfl_xor(accO, 2);
        accE += __shfl_xor(accE, 1);
        accE += __shfl_xor(accE, 2);
        if (q == 0) {
            atomicAdd(&rw[(i0 + li) * LWALK + colO], accO * FP8_INV2);
            atomicAdd(&rw[(i0 + li) * LWALK + colE], accE * FP8_INV2);
        }
    }
}

// ---------- final linear ----------
__global__ void linear_k(const float* __restrict__ rw, const float* __restrict__ W,
                         const float* __restrict__ b, float* __restrict__ out) {
    int i = blockIdx.x * blockDim.x + threadIdx.x;
    if (i >= NNODES * ODIM) return;
    int s = i >> 3, d = i & 7;
    float acc = b[d];
#pragma unroll
    for (int k = 0; k < LWALK; ++k)
        acc = fmaf(rw[s * LWALK + k], W[d * LWALK + k], acc);
    out[i] = acc;
}

extern "C" void kernel_launch(void* const* d_in, const int* in_sizes, int n_in,
                              void* d_out, int out_size, void* d_ws, size_t ws_size,
                              hipStream_t stream) {
    const void* ei = d_in[0];
    int E = in_sizes[0] / 2;
    const float* W = (const float*)d_in[2];
    const float* bias = (const float*)d_in[3];
    float* out = (float*)d_out;

    char* ws = (char*)d_ws;
    size_t off = 0;
    auto alloc = [&](size_t bytes) -> char* {
        char* p = ws + off;
        off = (off + bytes + 255) & ~(size_t)255;
        return p;
    };
    int* flag = (int*)alloc(4);
    int* deg = (int*)alloc(NNODES * 4);
    int* cnt = (int*)alloc(NNODES * 4);
    int* rowptr = (int*)alloc((NNODES + 1) * 4);
    int* cursor = (int*)alloc(NNODES * 4);
    uint2* epad = (uint2*)alloc(((size_t)E + 8 * NNODES) * 8);
    float* rw = (float*)alloc(NNODES * LWALK * 4);
    __half* Xh = (__half*)alloc((size_t)NNODES * NNODES * 2);
    unsigned char* A = (unsigned char*)alloc((size_t)NNODES * NNODES);
    unsigned char* B = (unsigned char*)alloc((size_t)NNODES * NNODES);
    unsigned char* C = (unsigned char*)alloc((size_t)NNODES * NNODES);

    (void)hipMemsetAsync(deg, 0, NNODES * 4, stream);
    (void)hipMemsetAsync(cnt, 0, NNODES * 4, stream);
    (void)hipMemsetAsync(rw, 0, NNODES * LWALK * 4, stream);
    detect_fmt_k<<<1, 64, 0, stream>>>(ei, E, flag);
    build_deg_cnt_k<<<(E + 255) / 256, 256, 0, stream>>>(ei, E, deg, cnt, flag);
    scan_k<<<1, 1024, 0, stream>>>(cnt, rowptr, cursor);
    fill_csr_k<<<(E + 255) / 256, 256, 0, stream>>>(ei, E, deg, cursor, epad, flag);
    pad_fill_k<<<(NNODES + 255) / 256, 256, 0, stream>>>(rowptr, cursor, epad);

    // X1 = P^T (fp16) via zero + scatter
    zero_k<<<NNODES * (NNODES / 8) / 256, 256, 0, stream>>>((uint4n*)Xh);
    x1scatter_k<<<(E + 255) / 256, 256, 0, stream>>>(ei, E, deg, Xh, flag);

    // X2 (fp8) from X1; diags k=1,2
    spmm_h8_k<<<NNODES * 8 / 4, 256, 0, stream>>>(Xh, A, rowptr, epad, rw);

    // fp8 chain with fused pairdiags. Rotation: X2=A,X3=B,X4=C,X5=A,X6=B,X7=C,X8=A
    const int SG = 4096;  // 4096 c x 4 slabs / 4 waves
    // X3 = P^T X2 : A->B, diag k=3 (col2)
    fused8_k<<<SG, 256, 0, stream>>>(A, B, rowptr, epad, rw, 2, nullptr, nullptr, 0, 0, SG);
    // X4 : B->C, diag k=4
    fused8_k<<<SG, 256, 0, stream>>>(B, C, rowptr, epad, rw, 3, nullptr, nullptr, 0, 0, SG);
    // X5 : C->A, diag k=5
    fused8_k<<<SG, 256, 0, stream>>>(C, A, rowptr, epad, rw, 4, nullptr, nullptr, 0, 0, SG);
    // X6 : A->B, diag k=6  + pair(X5=A, X4=C): k=9 (col8), k=10 (col9)
    fused8_k<<<SG + 1024, 256, 0, stream>>>(A, B, rowptr, epad, rw, 5, A, C, 8, 9, SG);
    // X7 : B->C, diag k=7  + pair(X6=B, X5=A): k=11, k=12
    fused8_k<<<SG + 1024, 256, 0, stream>>>(B, C, rowptr, epad, rw, 6, B, A, 10, 11, SG);
    // X8 : C->A, diag k=8  + pair(X7=C, X6=B): k=13, k=14
    fused8_k<<<SG + 1024, 256, 0, stream>>>(C, A, rowptr, epad, rw, 7, C, B, 12, 13, SG);
    // pair-only (X8=A, X7=C): k=15, k=16
    fused8_k<<<1024, 256, 0, stream>>>(nullptr, nullptr, rowptr, epad, rw, 0, A, C, 14, 15, 0);

    linear_k<<<(NNODES * ODIM + 255) / 256, 256, 0, stream>>>(rw, W, bias, out);
}

// Round 11
// 304.754 us; speedup vs baseline: 1.5771x; 1.0590x over previous
//
#include <hip/hip_runtime.h>
#include <hip/hip_fp16.h>
#include <hip/hip_fp8.h>

#define NNODES 4096
#define LWALK 16
#define ODIM 8

#define FP8_SCALE 256.0f
#define FP8_INV   0.00390625f          // 1/256
#define FP8_INV2  1.52587890625e-05f   // 1/65536

typedef unsigned int uint4n __attribute__((ext_vector_type(4)));
typedef unsigned int uint2n __attribute__((ext_vector_type(2)));
typedef float float2n __attribute__((ext_vector_type(2)));

// ---------- fp8 helpers ----------
__device__ __forceinline__ void dec8f(unsigned int lo, unsigned int hi, float* f) {
#if __has_builtin(__builtin_amdgcn_cvt_pk_f32_fp8)
    float2n p;
    p = __builtin_amdgcn_cvt_pk_f32_fp8((int)lo, false); f[0] = p.x; f[1] = p.y;
    p = __builtin_amdgcn_cvt_pk_f32_fp8((int)lo, true);  f[2] = p.x; f[3] = p.y;
    p = __builtin_amdgcn_cvt_pk_f32_fp8((int)hi, false); f[4] = p.x; f[5] = p.y;
    p = __builtin_amdgcn_cvt_pk_f32_fp8((int)hi, true);  f[6] = p.x; f[7] = p.y;
#else
    unsigned int w[2] = {lo, hi};
    const unsigned char* b = (const unsigned char*)w;
#pragma unroll
    for (int i = 0; i < 8; ++i) {
        __hip_fp8_e4m3 t; t.__x = b[i]; f[i] = (float)t;
    }
#endif
}

__device__ __forceinline__ void enc8f(const float* a, unsigned int* lo,
                                      unsigned int* hi) {
#if __has_builtin(__builtin_amdgcn_cvt_pk_fp8_f32)
    int l = 0, h = 0;
    l = __builtin_amdgcn_cvt_pk_fp8_f32(a[0], a[1], l, false);
    l = __builtin_amdgcn_cvt_pk_fp8_f32(a[2], a[3], l, true);
    h = __builtin_amdgcn_cvt_pk_fp8_f32(a[4], a[5], h, false);
    h = __builtin_amdgcn_cvt_pk_fp8_f32(a[6], a[7], h, true);
    *lo = (unsigned int)l; *hi = (unsigned int)h;
#else
    unsigned char b[8];
#pragma unroll
    for (int i = 0; i < 8; ++i)
        b[i] = __hip_cvt_float_to_fp8(a[i], __HIP_SATFINITE, __HIP_E4M3);
    unsigned int w[2];
    __builtin_memcpy(w, b, 8);
    *lo = w[0]; *hi = w[1];
#endif
}

__device__ __forceinline__ void dec16f(uint4n w, float* f) {
    dec8f(w.x, w.y, f);
    dec8f(w.z, w.w, f + 8);
}

__device__ __forceinline__ uint4n enc16f(const float* a) {
    uint4n o;
    unsigned int lo, hi;
    enc8f(a, &lo, &hi);     o.x = lo; o.y = hi;
    enc8f(a + 8, &lo, &hi); o.z = lo; o.w = hi;
    return o;
}

// ---------- edge-index dtype detection ----------
__global__ void detect_fmt_k(const void* ei, int E, int* flag) {
    if (blockIdx.x == 0 && threadIdx.x == 0) {
        const long long* p = (const long long*)ei;
        int ok = 1;
        for (int i = 0; i < 64; ++i) {
            long long v = p[i];
            if (v < 0 || v >= NNODES) { ok = 0; break; }
        }
        *flag = ok;
    }
}

__device__ __forceinline__ int load_idx(const void* p, int i, int fmt) {
    if (fmt) return (int)((const long long*)p)[i];
    return ((const int*)p)[i];
}

__global__ void build_deg_cnt_k(const void* ei, int E, int* deg, int* cnt,
                                const int* fmt) {
    int e = blockIdx.x * blockDim.x + threadIdx.x;
    if (e >= E) return;
    int f = *fmt;
    int r = load_idx(ei, e, f);
    int c = load_idx(ei, E + e, f);
    atomicAdd(&deg[r], 1);
    atomicAdd(&cnt[c], 1);
}

__global__ void scan_k(const int* __restrict__ cnt, int* __restrict__ rowptr,
                       int* __restrict__ cursor) {
    __shared__ int sm[1024];
    int tid = threadIdx.x;
    int v0 = (cnt[4 * tid + 0] + 7) & ~7;
    int v1 = (cnt[4 * tid + 1] + 7) & ~7;
    int v2 = (cnt[4 * tid + 2] + 7) & ~7;
    int v3 = (cnt[4 * tid + 3] + 7) & ~7;
    int tsum = v0 + v1 + v2 + v3;
    sm[tid] = tsum;
    __syncthreads();
    int val = tsum;
    for (int off = 1; off < 1024; off <<= 1) {
        int t = (tid >= off) ? sm[tid - off] : 0;
        __syncthreads();
        val += t;
        sm[tid] = val;
        __syncthreads();
    }
    int excl = val - tsum;
    int p0 = excl, p1 = excl + v0, p2 = p1 + v1, p3 = p2 + v2;
    rowptr[4 * tid + 0] = p0; rowptr[4 * tid + 1] = p1;
    rowptr[4 * tid + 2] = p2; rowptr[4 * tid + 3] = p3;
    cursor[4 * tid + 0] = p0; cursor[4 * tid + 1] = p1;
    cursor[4 * tid + 2] = p2; cursor[4 * tid + 3] = p3;
    if (tid == 1023) rowptr[4096] = val;
}

__global__ void fill_csr_k(const void* ei, int E, const int* __restrict__ deg,
                           int* cursor, uint2* __restrict__ epad, const int* fmt) {
    int e = blockIdx.x * blockDim.x + threadIdx.x;
    if (e >= E) return;
    int f = *fmt;
    int r = load_idx(ei, e, f);
    int c = load_idx(ei, E + e, f);
    int pos = atomicAdd(&cursor[c], 1);
    int d = deg[r];
    float v = 1.0f / (float)(d < 1 ? 1 : d);
    epad[pos] = make_uint2((unsigned)r, __float_as_uint(v));
}

__global__ void pad_fill_k(const int* __restrict__ rowptr,
                           const int* __restrict__ cursor,
                           uint2* __restrict__ epad) {
    int c = blockIdx.x * blockDim.x + threadIdx.x;
    if (c >= NNODES) return;
    for (int p = cursor[c]; p < rowptr[c + 1]; ++p)
        epad[p] = make_uint2(0u, 0u);
}

// ---------- X2 = (P^T)^2 via two-level sparse CSR walk; diag k=1,2 fused ------
// Row c of X2 = sum_{e1:(r->c), val v} sum_{e2:(s->r), val w} v*w at col s.
// Accumulate in a 16KB LDS fp32 row; quantize *FP8_SCALE to fp8 on store.
__global__ __launch_bounds__(256) void x2build_k(
    const int* __restrict__ rowptr, const uint2* __restrict__ epad,
    unsigned char* __restrict__ Y8, float* __restrict__ rw) {
    __shared__ float row[NNODES];
    __shared__ float dia1;
    const int c = blockIdx.x;
    const int t = threadIdx.x;
    for (int i = t; i < NNODES; i += 256) row[i] = 0.f;
    if (t == 0) dia1 = 0.f;
    __syncthreads();
    const int beg = rowptr[c], end = rowptr[c + 1];
    for (int i1 = beg + t; i1 < end; i1 += 256) {
        uint2 e1 = epad[i1];
        float v = __uint_as_float(e1.y);
        if (v != 0.f) {
            int r = (int)e1.x;
            if (r == c) atomicAdd(&dia1, v);
            int b2 = rowptr[r], n2 = rowptr[r + 1];
            for (int j = b2; j < n2; ++j) {
                uint2 e2 = epad[j];
                float w = __uint_as_float(e2.y);
                if (w != 0.f) atomicAdd(&row[e2.x], v * w);
            }
        }
    }
    __syncthreads();
    if (t == 0) {
        rw[c * LWALK + 0] = dia1;       // diag k=1 (exact fp32)
        rw[c * LWALK + 1] = row[c];     // diag k=2 (fp32, pre-quantize)
    }
    float f[16];
    const int base = t * 16;
#pragma unroll
    for (int u = 0; u < 16; ++u) f[u] = row[base + u] * FP8_SCALE;
    uint4n o = enc16f(f);
    __builtin_nontemporal_store(o, (uint4n*)(Y8 + (size_t)c * NNODES + base));
}

// ---------- fused fp8 SpMM (+optional pairdiag in appended blocks) ----------
__global__ __launch_bounds__(256) void fused8_k(
    const unsigned char* __restrict__ X8, unsigned char* __restrict__ Y8,
    const int* __restrict__ rowptr, const uint2* __restrict__ epad,
    float* __restrict__ rw, int kcol,
    const unsigned char* __restrict__ PA, const unsigned char* __restrict__ PB,
    int colO, int colE, int nspmm) {
    __shared__ __half bt[64][66];
    __shared__ __half ct[64][66];
    const int bid = blockIdx.x;
    if (bid < nspmm) {
        const int slab = bid & 3;
        const int lane = threadIdx.x & 63;
        const int c =
            __builtin_amdgcn_readfirstlane((bid >> 2) * 4 + (threadIdx.x >> 6));
        const int colo = slab * 1024 + lane * 16;  // fp8 byte offset
        const unsigned char* Xs = X8 + colo;
        const int beg = rowptr[c], end = rowptr[c + 1];
        float a[16];
#pragma unroll
        for (int u = 0; u < 16; ++u) a[u] = 0.f;
        for (int e = beg; e < end; e += 8) {
            uint2 ed[8];
#pragma unroll
            for (int j = 0; j < 8; ++j) ed[j] = epad[e + j];
            uint4n x[8];
#pragma unroll
            for (int j = 0; j < 8; ++j)
                x[j] = *(const uint4n*)(Xs + (size_t)ed[j].x * NNODES);
#pragma unroll
            for (int j = 0; j < 8; ++j) {
                float v = __uint_as_float(ed[j].y);
                float f[16];
                dec16f(x[j], f);
#pragma unroll
                for (int u = 0; u < 16; ++u) a[u] = fmaf(f[u], v, a[u]);
            }
        }
        if ((c >> 10) == slab && lane == ((c & 1023) >> 4)) {
            float d = 0.f;
#pragma unroll
            for (int u = 0; u < 16; ++u)
                if ((c & 15) == u) d = a[u];
            rw[c * LWALK + kcol] = d * FP8_INV;
        }
        uint4n o = enc16f(a);
        __builtin_nontemporal_store(o, (uint4n*)(Y8 + (size_t)c * NNODES + colo));
    } else {
        const int pb = bid - nspmm;      // 1024 pair blocks
        const int i0 = (pb & 63) * 64;
        const int Jbeg = (pb >> 6) * (NNODES / 16);
        const int Jend = Jbeg + (NNODES / 16);
        const int t = threadIdx.x;
        const int li = t >> 2;
        const int q = t & 3;
        const int c0 = q * 16;
        float accO = 0.f, accE = 0.f;
        for (int J = Jbeg; J < Jend; J += 64) {
            uint4n b16 = __builtin_nontemporal_load(
                (const uint4n*)(PB + (size_t)(J + li) * NNODES + i0 + c0));
            uint4n g16 = __builtin_nontemporal_load(
                (const uint4n*)(PA + (size_t)(J + li) * NNODES + i0 + c0));
            __syncthreads();
            float bf[16], gf[16];
            dec16f(b16, bf);
            dec16f(g16, gf);
#pragma unroll
            for (int s = 0; s < 16; ++s) {
                bt[c0 + s][li] = __float2half(bf[s]);  // fp8 values exact in fp16
                ct[c0 + s][li] = __float2half(gf[s]);
            }
            __syncthreads();
            uint4n a16 = __builtin_nontemporal_load(
                (const uint4n*)(PA + (size_t)(i0 + li) * NNODES + J + c0));
            float af[16];
            dec16f(a16, af);
#pragma unroll
            for (int s = 0; s < 16; ++s) {
                accO = fmaf(af[s], __half2float(bt[li][c0 + s]), accO);
                accE = fmaf(af[s], __half2float(ct[li][c0 + s]), accE);
            }
        }
        accO += __shfl_xor(accO, 1);
        accO += __shfl_xor(accO, 2);
        accE += __shfl_xor(accE, 1);
        accE += __shfl_xor(accE, 2);
        if (q == 0) {
            atomicAdd(&rw[(i0 + li) * LWALK + colO], accO * FP8_INV2);
            atomicAdd(&rw[(i0 + li) * LWALK + colE], accE * FP8_INV2);
        }
    }
}

// ---------- final linear ----------
__global__ void linear_k(const float* __restrict__ rw, const float* __restrict__ W,
                         const float* __restrict__ b, float* __restrict__ out) {
    int i = blockIdx.x * blockDim.x + threadIdx.x;
    if (i >= NNODES * ODIM) return;
    int s = i >> 3, d = i & 7;
    float acc = b[d];
#pragma unroll
    for (int k = 0; k < LWALK; ++k)
        acc = fmaf(rw[s * LWALK + k], W[d * LWALK + k], acc);
    out[i] = acc;
}

extern "C" void kernel_launch(void* const* d_in, const int* in_sizes, int n_in,
                              void* d_out, int out_size, void* d_ws, size_t ws_size,
                              hipStream_t stream) {
    const void* ei = d_in[0];
    int E = in_sizes[0] / 2;
    const float* W = (const float*)d_in[2];
    const float* bias = (const float*)d_in[3];
    float* out = (float*)d_out;

    char* ws = (char*)d_ws;
    size_t off = 0;
    auto alloc = [&](size_t bytes) -> char* {
        char* p = ws + off;
        off = (off + bytes + 255) & ~(size_t)255;
        return p;
    };
    int* flag = (int*)alloc(4);
    int* deg = (int*)alloc(NNODES * 4);
    int* cnt = (int*)alloc(NNODES * 4);
    int* rowptr = (int*)alloc((NNODES + 1) * 4);
    int* cursor = (int*)alloc(NNODES * 4);
    uint2* epad = (uint2*)alloc(((size_t)E + 8 * NNODES) * 8);
    float* rw = (float*)alloc(NNODES * LWALK * 4);
    unsigned char* A = (unsigned char*)alloc((size_t)NNODES * NNODES);
    unsigned char* B = (unsigned char*)alloc((size_t)NNODES * NNODES);
    unsigned char* C = (unsigned char*)alloc((size_t)NNODES * NNODES);

    (void)hipMemsetAsync(deg, 0, NNODES * 4, stream);
    (void)hipMemsetAsync(cnt, 0, NNODES * 4, stream);
    (void)hipMemsetAsync(rw, 0, NNODES * LWALK * 4, stream);
    detect_fmt_k<<<1, 64, 0, stream>>>(ei, E, flag);
    build_deg_cnt_k<<<(E + 255) / 256, 256, 0, stream>>>(ei, E, deg, cnt, flag);
    scan_k<<<1, 1024, 0, stream>>>(cnt, rowptr, cursor);
    fill_csr_k<<<(E + 255) / 256, 256, 0, stream>>>(ei, E, deg, cursor, epad, flag);
    pad_fill_k<<<(NNODES + 255) / 256, 256, 0, stream>>>(rowptr, cursor, epad);

    // X2 (fp8, scaled) directly from the CSR; diags k=1,2 fused. X1 never built.
    x2build_k<<<NNODES, 256, 0, stream>>>(rowptr, epad, A, rw);

    // fp8 chain with fused pairdiags. Rotation: X2=A,X3=B,X4=C,X5=A,X6=B,X7=C,X8=A
    const int SG = 4096;  // 4096 c x 4 slabs / 4 waves
    // X3 : A->B, diag k=3 (col2)
    fused8_k<<<SG, 256, 0, stream>>>(A, B, rowptr, epad, rw, 2, nullptr, nullptr, 0, 0, SG);
    // X4 : B->C, diag k=4
    fused8_k<<<SG, 256, 0, stream>>>(B, C, rowptr, epad, rw, 3, nullptr, nullptr, 0, 0, SG);
    // X5 : C->A, diag k=5
    fused8_k<<<SG, 256, 0, stream>>>(C, A, rowptr, epad, rw, 4, nullptr, nullptr, 0, 0, SG);
    // X6 : A->B, diag k=6  + pair(X5=A, X4=C): k=9 (col8), k=10 (col9)
    fused8_k<<<SG + 1024, 256, 0, stream>>>(A, B, rowptr, epad, rw, 5, A, C, 8, 9, SG);
    // X7 : B->C, diag k=7  + pair(X6=B, X5=A): k=11, k=12
    fused8_k<<<SG + 1024, 256, 0, stream>>>(B, C, rowptr, epad, rw, 6, B, A, 10, 11, SG);
    // X8 : C->A, diag k=8  + pair(X7=C, X6=B): k=13, k=14
    fused8_k<<<SG + 1024, 256, 0, stream>>>(C, A, rowptr, epad, rw, 7, C, B, 12, 13, SG);
    // pair-only (X8=A, X7=C): k=15, k=16
    fused8_k<<<1024, 256, 0, stream>>>(nullptr, nullptr, rowptr, epad, rw, 0, A, C, 14, 15, 0);

    linear_k<<<(NNODES * ODIM + 255) / 256, 256, 0, stream>>>(rw, W, bias, out);
}

// Round 12
// 295.333 us; speedup vs baseline: 1.6274x; 1.0319x over previous
//
#include <hip/hip_runtime.h>
#include <hip/hip_fp16.h>
#include <hip/hip_fp8.h>

#define NNODES 4096
#define LWALK 16
#define ODIM 8

#define FP8_SCALE 256.0f
#define FP8_INV   0.00390625f          // 1/256
#define FP8_INV2  1.52587890625e-05f   // 1/65536

typedef unsigned int uint4n __attribute__((ext_vector_type(4)));
typedef unsigned int uint2n __attribute__((ext_vector_type(2)));
typedef float float2n __attribute__((ext_vector_type(2)));

// ---------- fp8 helpers ----------
__device__ __forceinline__ void dec8f(unsigned int lo, unsigned int hi, float* f) {
#if __has_builtin(__builtin_amdgcn_cvt_pk_f32_fp8)
    float2n p;
    p = __builtin_amdgcn_cvt_pk_f32_fp8((int)lo, false); f[0] = p.x; f[1] = p.y;
    p = __builtin_amdgcn_cvt_pk_f32_fp8((int)lo, true);  f[2] = p.x; f[3] = p.y;
    p = __builtin_amdgcn_cvt_pk_f32_fp8((int)hi, false); f[4] = p.x; f[5] = p.y;
    p = __builtin_amdgcn_cvt_pk_f32_fp8((int)hi, true);  f[6] = p.x; f[7] = p.y;
#else
    unsigned int w[2] = {lo, hi};
    const unsigned char* b = (const unsigned char*)w;
#pragma unroll
    for (int i = 0; i < 8; ++i) {
        __hip_fp8_e4m3 t; t.__x = b[i]; f[i] = (float)t;
    }
#endif
}

__device__ __forceinline__ void enc8f(const float* a, unsigned int* lo,
                                      unsigned int* hi) {
#if __has_builtin(__builtin_amdgcn_cvt_pk_fp8_f32)
    int l = 0, h = 0;
    l = __builtin_amdgcn_cvt_pk_fp8_f32(a[0], a[1], l, false);
    l = __builtin_amdgcn_cvt_pk_fp8_f32(a[2], a[3], l, true);
    h = __builtin_amdgcn_cvt_pk_fp8_f32(a[4], a[5], h, false);
    h = __builtin_amdgcn_cvt_pk_fp8_f32(a[6], a[7], h, true);
    *lo = (unsigned int)l; *hi = (unsigned int)h;
#else
    unsigned char b[8];
#pragma unroll
    for (int i = 0; i < 8; ++i)
        b[i] = __hip_cvt_float_to_fp8(a[i], __HIP_SATFINITE, __HIP_E4M3);
    unsigned int w[2];
    __builtin_memcpy(w, b, 8);
    *lo = w[0]; *hi = w[1];
#endif
}

__device__ __forceinline__ void dec16f(uint4n w, float* f) {
    dec8f(w.x, w.y, f);
    dec8f(w.z, w.w, f + 8);
}

__device__ __forceinline__ uint4n enc16f(const float* a) {
    uint4n o;
    unsigned int lo, hi;
    enc8f(a, &lo, &hi);     o.x = lo; o.y = hi;
    enc8f(a + 8, &lo, &hi); o.z = lo; o.w = hi;
    return o;
}

// ---------- edge-index dtype detection ----------
__global__ void detect_fmt_k(const void* ei, int E, int* flag) {
    if (blockIdx.x == 0 && threadIdx.x == 0) {
        const long long* p = (const long long*)ei;
        int ok = 1;
        for (int i = 0; i < 64; ++i) {
            long long v = p[i];
            if (v < 0 || v >= NNODES) { ok = 0; break; }
        }
        *flag = ok;
    }
}

__device__ __forceinline__ int load_idx(const void* p, int i, int fmt) {
    if (fmt) return (int)((const long long*)p)[i];
    return ((const int*)p)[i];
}

__global__ void build_deg_cnt_k(const void* ei, int E, int* deg, int* cnt,
                                const int* fmt) {
    int e = blockIdx.x * blockDim.x + threadIdx.x;
    if (e >= E) return;
    int f = *fmt;
    int r = load_idx(ei, e, f);
    int c = load_idx(ei, E + e, f);
    atomicAdd(&deg[r], 1);
    atomicAdd(&cnt[c], 1);
}

// ---------- exclusive scan over padded (multiple-of-4) counts ----------
__global__ void scan_k(const int* __restrict__ cnt, int* __restrict__ rowptr,
                       int* __restrict__ cursor) {
    __shared__ int sm[1024];
    int tid = threadIdx.x;
    int v0 = (cnt[4 * tid + 0] + 3) & ~3;
    int v1 = (cnt[4 * tid + 1] + 3) & ~3;
    int v2 = (cnt[4 * tid + 2] + 3) & ~3;
    int v3 = (cnt[4 * tid + 3] + 3) & ~3;
    int tsum = v0 + v1 + v2 + v3;
    sm[tid] = tsum;
    __syncthreads();
    int val = tsum;
    for (int off = 1; off < 1024; off <<= 1) {
        int t = (tid >= off) ? sm[tid - off] : 0;
        __syncthreads();
        val += t;
        sm[tid] = val;
        __syncthreads();
    }
    int excl = val - tsum;
    int p0 = excl, p1 = excl + v0, p2 = p1 + v1, p3 = p2 + v2;
    rowptr[4 * tid + 0] = p0; rowptr[4 * tid + 1] = p1;
    rowptr[4 * tid + 2] = p2; rowptr[4 * tid + 3] = p3;
    cursor[4 * tid + 0] = p0; cursor[4 * tid + 1] = p1;
    cursor[4 * tid + 2] = p2; cursor[4 * tid + 3] = p3;
    if (tid == 1023) rowptr[4096] = val;
}

// ---------- fill CSR + zero padding slots (merged) ----------
__global__ void fill_pad_k(const void* ei, int E, const int* __restrict__ deg,
                           int* cursor, const int* __restrict__ rowptr,
                           uint2* __restrict__ epad, const int* fmt) {
    int e = blockIdx.x * blockDim.x + threadIdx.x;
    if (e < E) {
        int f = *fmt;
        int r = load_idx(ei, e, f);
        int c = load_idx(ei, E + e, f);
        int pos = atomicAdd(&cursor[c], 1);
        int d = deg[r];
        float v = 1.0f / (float)(d < 1 ? 1 : d);
        epad[pos] = make_uint2((unsigned)r, __float_as_uint(v));
    } else if (e < E + NNODES) {
        // one tail thread per node: zero its padding slots (cursor final after
        // grid-wide... NOT safe in same launch). handled below in pad pass.
    }
}

__global__ void pad_fill_k(const int* __restrict__ rowptr,
                           const int* __restrict__ cursor,
                           uint2* __restrict__ epad) {
    int c = blockIdx.x * blockDim.x + threadIdx.x;
    if (c >= NNODES) return;
    for (int p = cursor[c]; p < rowptr[c + 1]; ++p)
        epad[p] = make_uint2(0u, 0u);
}

// ---------- X2 = (P^T)^2 via two-level sparse CSR walk; diag k=1,2 fused ------
// Flattened: 256 threads = 16 e1-slots x 16 e2-lanes; all lanes active.
__global__ __launch_bounds__(256) void x2build_k(
    const int* __restrict__ rowptr, const uint2* __restrict__ epad,
    unsigned char* __restrict__ Y8, float* __restrict__ rw) {
    __shared__ float row[NNODES];
    __shared__ float dia1;
    const int c = blockIdx.x;
    const int t = threadIdx.x;
    for (int i = t; i < NNODES; i += 256) row[i] = 0.f;
    if (t == 0) dia1 = 0.f;
    __syncthreads();
    const int beg = rowptr[c], end = rowptr[c + 1];
    const int g = t >> 4;        // e1 slot [0,16)
    const int l = t & 15;        // e2 lane [0,16)
    for (int i1 = beg + g; i1 < end; i1 += 16) {
        uint2 e1 = epad[i1];
        float v = __uint_as_float(e1.y);
        if (v != 0.f) {
            int r = (int)e1.x;
            if (r == c && l == 0) atomicAdd(&dia1, v);
            int b2 = rowptr[r], n2 = rowptr[r + 1];
            for (int j = b2 + l; j < n2; j += 16) {
                uint2 e2 = epad[j];
                float w = __uint_as_float(e2.y);
                if (w != 0.f) atomicAdd(&row[e2.x], v * w);
            }
        }
    }
    __syncthreads();
    if (t == 0) {
        rw[c * LWALK + 0] = dia1;       // diag k=1 (exact fp32)
        rw[c * LWALK + 1] = row[c];     // diag k=2 (fp32, pre-quantize)
    }
    float f[16];
    const int base = t * 16;
#pragma unroll
    for (int u = 0; u < 16; ++u) f[u] = row[base + u] * FP8_SCALE;
    uint4n o = enc16f(f);
    __builtin_nontemporal_store(o, (uint4n*)(Y8 + (size_t)c * NNODES + base));
}

// ---------- fused fp8 SpMM (+optional pairdiag in appended blocks) ----------
__global__ __launch_bounds__(256) void fused8_k(
    const unsigned char* __restrict__ X8, unsigned char* __restrict__ Y8,
    const int* __restrict__ rowptr, const uint2* __restrict__ epad,
    float* __restrict__ rw, int kcol,
    const unsigned char* __restrict__ PA, const unsigned char* __restrict__ PB,
    int colO, int colE, int nspmm) {
    __shared__ __half bt[64][66];
    __shared__ __half ct[64][66];
    const int bid = blockIdx.x;
    if (bid < nspmm) {
        const int slab = bid & 3;
        const int lane = threadIdx.x & 63;
        const int c =
            __builtin_amdgcn_readfirstlane((bid >> 2) * 4 + (threadIdx.x >> 6));
        const int colo = slab * 1024 + lane * 16;  // fp8 byte offset
        const unsigned char* Xs = X8 + colo;
        const int beg = rowptr[c], end = rowptr[c + 1];  // padded %4
        float a[16];
#pragma unroll
        for (int u = 0; u < 16; ++u) a[u] = 0.f;
        for (int e = beg; e < end; e += 4) {
            uint2 ed[4];
#pragma unroll
            for (int j = 0; j < 4; ++j) ed[j] = epad[e + j];
            uint4n x[4];
#pragma unroll
            for (int j = 0; j < 4; ++j)
                x[j] = *(const uint4n*)(Xs + (size_t)ed[j].x * NNODES);
#pragma unroll
            for (int j = 0; j < 4; ++j) {
                float v = __uint_as_float(ed[j].y);
                float f[16];
                dec16f(x[j], f);
#pragma unroll
                for (int u = 0; u < 16; ++u) a[u] = fmaf(f[u], v, a[u]);
            }
        }
        if ((c >> 10) == slab && lane == ((c & 1023) >> 4)) {
            float d = 0.f;
#pragma unroll
            for (int u = 0; u < 16; ++u)
                if ((c & 15) == u) d = a[u];
            rw[c * LWALK + kcol] = d * FP8_INV;
        }
        uint4n o = enc16f(a);
        __builtin_nontemporal_store(o, (uint4n*)(Y8 + (size_t)c * NNODES + colo));
    } else {
        const int pb = bid - nspmm;      // 1024 pair blocks
        const int i0 = (pb & 63) * 64;
        const int Jbeg = (pb >> 6) * (NNODES / 16);
        const int Jend = Jbeg + (NNODES / 16);
        const int t = threadIdx.x;
        const int li = t >> 2;
        const int q = t & 3;
        const int c0 = q * 16;
        float accO = 0.f, accE = 0.f;
        for (int J = Jbeg; J < Jend; J += 64) {
            uint4n b16 = __builtin_nontemporal_load(
                (const uint4n*)(PB + (size_t)(J + li) * NNODES + i0 + c0));
            uint4n g16 = __builtin_nontemporal_load(
                (const uint4n*)(PA + (size_t)(J + li) * NNODES + i0 + c0));
            __syncthreads();
            float bf[16], gf[16];
            dec16f(b16, bf);
            dec16f(g16, gf);
#pragma unroll
            for (int s = 0; s < 16; ++s) {
                bt[c0 + s][li] = __float2half(bf[s]);  // fp8 values exact in fp16
                ct[c0 + s][li] = __float2half(gf[s]);
            }
            __syncthreads();
            uint4n a16 = __builtin_nontemporal_load(
                (const uint4n*)(PA + (size_t)(i0 + li) * NNODES + J + c0));
            float af[16];
            dec16f(a16, af);
#pragma unroll
            for (int s = 0; s < 16; ++s) {
                accO = fmaf(af[s], __half2float(bt[li][c0 + s]), accO);
                accE = fmaf(af[s], __half2float(ct[li][c0 + s]), accE);
            }
        }
        accO += __shfl_xor(accO, 1);
        accO += __shfl_xor(accO, 2);
        accE += __shfl_xor(accE, 1);
        accE += __shfl_xor(accE, 2);
        if (q == 0) {
            atomicAdd(&rw[(i0 + li) * LWALK + colO], accO * FP8_INV2);
            atomicAdd(&rw[(i0 + li) * LWALK + colE], accE * FP8_INV2);
        }
    }
}

// ---------- final: pairdiag(X8,X7) for k=15,16 + linear, one launch ----------
__global__ __launch_bounds__(256) void finale_k(
    const unsigned char* __restrict__ PA, const unsigned char* __restrict__ PB,
    float* __restrict__ rw, const float* __restrict__ W,
    const float* __restrict__ b, float* __restrict__ out, int npair) {
    __shared__ __half bt[64][66];
    __shared__ __half ct[64][66];
    const int bid = blockIdx.x;
    if (bid < npair) {
        const int pb = bid;
        const int i0 = (pb & 63) * 64;
        const int Jbeg = (pb >> 6) * (NNODES / 16);
        const int Jend = Jbeg + (NNODES / 16);
        const int t = threadIdx.x;
        const int li = t >> 2;
        const int q = t & 3;
        const int c0 = q * 16;
        float accO = 0.f, accE = 0.f;
        for (int J = Jbeg; J < Jend; J += 64) {
            uint4n b16 = __builtin_nontemporal_load(
                (const uint4n*)(PB + (size_t)(J + li) * NNODES + i0 + c0));
            uint4n g16 = __builtin_nontemporal_load(
                (const uint4n*)(PA + (size_t)(J + li) * NNODES + i0 + c0));
            __syncthreads();
            float bf[16], gf[16];
            dec16f(b16, bf);
            dec16f(g16, gf);
#pragma unroll
            for (int s = 0; s < 16; ++s) {
                bt[c0 + s][li] = __float2half(bf[s]);
                ct[c0 + s][li] = __float2half(gf[s]);
            }
            __syncthreads();
            uint4n a16 = __builtin_nontemporal_load(
                (const uint4n*)(PA + (size_t)(i0 + li) * NNODES + J + c0));
            float af[16];
            dec16f(a16, af);
#pragma unroll
            for (int s = 0; s < 16; ++s) {
                accO = fmaf(af[s], __half2float(bt[li][c0 + s]), accO);
                accE = fmaf(af[s], __half2float(ct[li][c0 + s]), accE);
            }
        }
        accO += __shfl_xor(accO, 1);
        accO += __shfl_xor(accO, 2);
        accE += __shfl_xor(accE, 1);
        accE += __shfl_xor(accE, 2);
        if (q == 0) {
            atomicAdd(&rw[(i0 + li) * LWALK + 14], accO * FP8_INV2);
            atomicAdd(&rw[(i0 + li) * LWALK + 15], accE * FP8_INV2);
        }
    }
    // linear (all blocks; runs after this block's pair work; rw rows other
    // than cols 14/15 are final, and cols 14/15 are computed by pair blocks
    // possibly still running elsewhere -> must NOT read them here.
    // So linear is only done by pair blocks for their own i-range AFTER
    // their own atomics; cross-block k=15/16 contributions come from other
    // J-chunks though. -> keep linear in the tail blocks only when npair==0.
}

// ---------- final linear (separate; needs all rw complete) ----------
__global__ void linear_k(const float* __restrict__ rw, const float* __restrict__ W,
                         const float* __restrict__ b, float* __restrict__ out) {
    int i = blockIdx.x * blockDim.x + threadIdx.x;
    if (i >= NNODES * ODIM) return;
    int s = i >> 3, d = i & 7;
    float acc = b[d];
#pragma unroll
    for (int k = 0; k < LWALK; ++k)
        acc = fmaf(rw[s * LWALK + k], W[d * LWALK + k], acc);
    out[i] = acc;
}

extern "C" void kernel_launch(void* const* d_in, const int* in_sizes, int n_in,
                              void* d_out, int out_size, void* d_ws, size_t ws_size,
                              hipStream_t stream) {
    const void* ei = d_in[0];
    int E = in_sizes[0] / 2;
    const float* W = (const float*)d_in[2];
    const float* bias = (const float*)d_in[3];
    float* out = (float*)d_out;

    char* ws = (char*)d_ws;
    size_t off = 0;
    auto alloc = [&](size_t bytes) -> char* {
        char* p = ws + off;
        off = (off + bytes + 255) & ~(size_t)255;
        return p;
    };
    int* flag = (int*)alloc(4);
    int* deg = (int*)alloc(NNODES * 4);
    int* cnt = (int*)alloc(NNODES * 4);
    int* rowptr = (int*)alloc((NNODES + 1) * 4);
    int* cursor = (int*)alloc(NNODES * 4);
    uint2* epad = (uint2*)alloc(((size_t)E + 4 * NNODES) * 8);
    float* rw = (float*)alloc(NNODES * LWALK * 4);
    unsigned char* A = (unsigned char*)alloc((size_t)NNODES * NNODES);
    unsigned char* B = (unsigned char*)alloc((size_t)NNODES * NNODES);
    unsigned char* C = (unsigned char*)alloc((size_t)NNODES * NNODES);

    (void)hipMemsetAsync(deg, 0, NNODES * 4, stream);
    (void)hipMemsetAsync(cnt, 0, NNODES * 4, stream);
    (void)hipMemsetAsync(rw, 0, NNODES * LWALK * 4, stream);
    detect_fmt_k<<<1, 64, 0, stream>>>(ei, E, flag);
    build_deg_cnt_k<<<(E + 255) / 256, 256, 0, stream>>>(ei, E, deg, cnt, flag);
    scan_k<<<1, 1024, 0, stream>>>(cnt, rowptr, cursor);
    fill_pad_k<<<(E + 255) / 256, 256, 0, stream>>>(ei, E, deg, cursor, rowptr,
                                                    epad, flag);
    pad_fill_k<<<(NNODES + 255) / 256, 256, 0, stream>>>(rowptr, cursor, epad);

    // X2 (fp8, scaled) directly from the CSR; diags k=1,2 fused.
    x2build_k<<<NNODES, 256, 0, stream>>>(rowptr, epad, A, rw);

    // fp8 chain with fused pairdiags. Rotation: X2=A,X3=B,X4=C,X5=A,X6=B,X7=C,X8=A
    const int SG = 4096;
    fused8_k<<<SG, 256, 0, stream>>>(A, B, rowptr, epad, rw, 2, nullptr, nullptr, 0, 0, SG);            // X3
    fused8_k<<<SG, 256, 0, stream>>>(B, C, rowptr, epad, rw, 3, nullptr, nullptr, 0, 0, SG);            // X4
    fused8_k<<<SG, 256, 0, stream>>>(C, A, rowptr, epad, rw, 4, nullptr, nullptr, 0, 0, SG);            // X5
    fused8_k<<<SG + 1024, 256, 0, stream>>>(A, B, rowptr, epad, rw, 5, A, C, 8, 9, SG);                 // X6 + k9,10
    fused8_k<<<SG + 1024, 256, 0, stream>>>(B, C, rowptr, epad, rw, 6, B, A, 10, 11, SG);               // X7 + k11,12
    fused8_k<<<SG + 1024, 256, 0, stream>>>(C, A, rowptr, epad, rw, 7, C, B, 12, 13, SG);               // X8 + k13,14
    finale_k<<<1024, 256, 0, stream>>>(A, C, rw, W, bias, out, 1024);                                   // k15,16
    linear_k<<<(NNODES * ODIM + 255) / 256, 256, 0, stream>>>(rw, W, bias, out);

    (void)fill_pad_k;  // silence unused-warning paths if any
}